// Round 9
// baseline (793.554 us; speedup 1.0000x reference)
//
#include <hip/hip_runtime.h>
#include <math.h>

#define NB 8
#define NPTS 4096
#define NCH 64
#define NOUT 64
#define KNN 16
#define HALFC 2048

#define GLOBAL_AS const __attribute__((address_space(1)))
#define LDS_AS __attribute__((address_space(3)))

typedef float v2f __attribute__((ext_vector_type(2)));

// ws layout in floats:
#define WS_SQ  0
#define WS_PT  (NB*NPTS)                       // 32768
#define WS_QT  (WS_PT + NB*NPTS*64)            // + 2097152
#define WS_IDX (WS_QT + NB*NPTS*64)            // int32 region, NB*NPTS*16 ints
// vh/ih (KNN halves' value/idx lists) ALIAS the Pt region: dead before k_pq.

// ---------------------------------------------------------------- K1: sq ----
__global__ __launch_bounds__(256) void k_sq(const float* __restrict__ fea,
                                            float* __restrict__ sq) {
    int g = blockIdx.x * 256 + threadIdx.x;      // 32768
    int b = g >> 12, n = g & 4095;
    const float* f = fea + (size_t)b * NCH * NPTS + n;
    float s = 0.f;
#pragma unroll
    for (int c = 0; c < NCH; ++c) s = fmaf(f[c * NPTS], f[c * NPTS], s);
    sq[g] = s;
}

// ------------------------------------------------------- K2: fused KNN ------
// r9: same structure as r8 (128-row panels x 2 col-halves, wave owns 32 rows,
// acc 8 rows x 8 cols per lane, DPP-shift insertion, half-lists merged by
// k_merge) with two changes:
//  1. gram/transform in PACKED fp32 (v_pk_fma_f32 via float2 elementwise fma)
//     -> 2048 VALU inst/tile/wave instead of 4096. Bitwise-identical IEEE FMA.
//  2. reg-staged colT prefetch (T14): global loads for tile t+1 issued BEFORE
//     gram(t); ds_write after the post-scan barrier -> HBM latency hides
//     under gram+scan instead of being exposed at a barrier.
__global__ __launch_bounds__(256, 2) void k_knn(const float* __restrict__ fea,
                                                const float* __restrict__ sq,
                                                float* __restrict__ vh,
                                                int* __restrict__ ih) {
    __shared__ __align__(16) float rowT[64][128];   // 32KB
    __shared__ __align__(16) float colT[64 * 128];  // 32KB (single buffer)

    const int b = blockIdx.z;
    const int half = blockIdx.y;
    const int n0 = blockIdx.x * 128;
    const int cbase = half * HALFC;
    const int tid = threadIdx.x;
    const int lane = tid & 63, w = tid >> 6;
    const int g = lane >> 4, p = lane & 15;
    const int rbase = w * 32 + g * 8;               // this lane's 8 rows
    const float* feab = fea + (size_t)b * NCH * NPTS;

    float4 pref[8];                                 // staged tile in regs
    auto ld_tile = [&](int m0) {                    // issue 8 global b128 loads
#pragma unroll
        for (int i = 0; i < 8; ++i) {
            int k = w * 8 + i;
            int c = 2 * k + (lane >> 5);
            int j = (lane & 31) * 4;
            pref[i] = *(const float4*)&feab[c * NPTS + m0 + j];
        }
    };
    auto wr_tile = [&]() {                          // regs -> colT
#pragma unroll
        for (int i = 0; i < 8; ++i)
            *(float4*)&colT[(w * 8 + i) * 256 + lane * 4] = pref[i];
    };

#pragma unroll
    for (int i = 0; i < 8; ++i) {
        int e = i * 1024 + tid * 4;
        int c = e >> 7, r = e & 127;
        *(float4*)&rowT[c][r] = *(const float4*)&feab[c * NPTS + n0 + r];
    }

    float lstv[8];                                  // row rbase+i list,
    int   lsti[8];                                  // lane p = p-th smallest
    float thr[8];                                   // group-uniform list min
#pragma unroll
    for (int i = 0; i < 8; ++i) {
        lstv[i] = -3.0e38f; lsti[i] = 0; thr[i] = -3.0e38f;
    }

    // insert (vv, col) into row-i list; group-uniform call; DPP shift-by-1
    auto ins = [&](int i, float vv, int col) {
        unsigned long long lt = __ballot(lstv[i] < vv);
        int pos = __popc((unsigned)((lt >> (g * 16)) & 0xFFFFu));
        int nv = __builtin_amdgcn_update_dpp(0, __float_as_int(lstv[i]),
                                             0x101, 0xF, 0xF, true);
        int ni = __builtin_amdgcn_update_dpp(0, lsti[i],
                                             0x101, 0xF, 0xF, true);
        if (p <= pos - 2)      { lstv[i] = __int_as_float(nv); lsti[i] = ni; }
        else if (p == pos - 1) { lstv[i] = vv; lsti[i] = col; }
    };

    // prologue: stage tile 0
    ld_tile(cbase);
    wr_tile();
    __syncthreads();

    for (int t = 0; t < 16; ++t) {
        const int m0 = cbase + t * 128;
        if (t < 15) ld_tile(m0 + 128);              // issue next-tile loads

        float4 sql = *(const float4*)&sq[b * NPTS + m0 + p * 4];
        float4 sqh = *(const float4*)&sq[b * NPTS + m0 + 64 + p * 4];

        v2f acc2[8][4];
        const v2f z2 = {0.f, 0.f};
#pragma unroll
        for (int i = 0; i < 8; ++i)
#pragma unroll
            for (int j = 0; j < 4; ++j) acc2[i][j] = z2;

#pragma unroll 2
        for (int c = 0; c < 64; ++c) {
            float4 ra = *(const float4*)&rowT[c][rbase];
            float4 rb = *(const float4*)&rowT[c][rbase + 4];
            float4 ca = *(const float4*)&colT[c * 128 + p * 4];
            float4 cb = *(const float4*)&colT[c * 128 + 64 + p * 4];
            float rr[8] = {ra.x, ra.y, ra.z, ra.w, rb.x, rb.y, rb.z, rb.w};
            v2f cc[4] = {{ca.x, ca.y}, {ca.z, ca.w},
                         {cb.x, cb.y}, {cb.z, cb.w}};
#pragma unroll
            for (int ri = 0; ri < 8; ++ri) {
                v2f rv = {rr[ri], rr[ri]};
#pragma unroll
                for (int cj = 0; cj < 4; ++cj)
                    acc2[ri][cj] =
                        __builtin_elementwise_fma(rv, cc[cj], acc2[ri][cj]);
            }
        }

        // dist = 2*G - sq[col], packed
        v2f nsq[4] = {{-sql.x, -sql.y}, {-sql.z, -sql.w},
                      {-sqh.x, -sqh.y}, {-sqh.z, -sqh.w}};
        const v2f two2 = {2.f, 2.f};
#pragma unroll
        for (int i = 0; i < 8; ++i)
#pragma unroll
            for (int j = 0; j < 4; ++j)
                acc2[i][j] =
                    __builtin_elementwise_fma(two2, acc2[i][j], nsq[j]);

        // ---- scan: 8 rows x 2 col-halves; lockstep pops across groups ----
#pragma unroll
        for (int i = 0; i < 8; ++i) {
#pragma unroll
            for (int h = 0; h < 2; ++h) {
                float v0 = acc2[i][h * 2 + 0].x, v1 = acc2[i][h * 2 + 0].y;
                float v2 = acc2[i][h * 2 + 1].x, v3 = acc2[i][h * 2 + 1].y;
                v2f m2 = __builtin_elementwise_max(acc2[i][h * 2 + 0],
                                                   acc2[i][h * 2 + 1]);
                float vm = fmaxf(m2.x, m2.y);
                unsigned long long bal = __ballot(vm > thr[i]);
                unsigned mg = (unsigned)((bal >> (g * 16)) & 0xFFFFull);
                while (__any(mg != 0u)) {
                    bool act = (mg != 0u);
                    int srcp = act ? (__ffs(mg) - 1) : 0;
                    mg &= (mg - 1u);                // 0 stays 0
                    int srcl = (g << 4) | srcp;
                    float b0 = __shfl(v0, srcl);    // 4 parallel bcasts
                    float b1 = __shfl(v1, srcl);
                    float b2 = __shfl(v2, srcl);
                    float b3 = __shfl(v3, srcl);
                    if (act) {
                        int cb = m0 + h * 64 + srcp * 4;
                        if (b0 > thr[i]) ins(i, b0, cb + 0);
                        if (b1 > thr[i]) ins(i, b1, cb + 1);
                        if (b2 > thr[i]) ins(i, b2, cb + 2);
                        if (b3 > thr[i]) ins(i, b3, cb + 3);
                    }
                }
                if (bal) thr[i] = __shfl(lstv[i], 0, 16);
            }
        }
        __syncthreads();            // all waves done reading colT
        if (t < 15) {
            wr_tile();              // write prefetched tile t+1
            __syncthreads();        // writes visible before next gram
        }
    }

#pragma unroll
    for (int i = 0; i < 8; ++i) {                   // descending lists
        int row = rbase + i;
        size_t base = ((size_t)(b * NPTS) + n0 + row) * 32 + half * 16;
        vh[base + (15 - p)] = lstv[i];
        ih[base + (15 - p)] = lsti[i];
    }
}

// --------------------------------- K2b: merge the two half-range lists -----
__global__ __launch_bounds__(256) void k_merge(const float* __restrict__ vh,
                                               const int* __restrict__ ih,
                                               int* __restrict__ idxout) {
    int row = blockIdx.x * 256 + threadIdx.x;       // 32768 rows
    const float* v = vh + (size_t)row * 32;         // [0..15] h0, [16..31] h1
    const int* ii = ih + (size_t)row * 32;
    size_t ob = (size_t)row * KNN;
    int i0 = 0, i1 = 0;
#pragma unroll
    for (int j = 0; j < KNN; ++j) {
        float v0 = (i0 < 16) ? v[i0] : -3.4e38f;
        float v1 = (i1 < 16) ? v[16 + i1] : -3.4e38f;
        bool t0 = (v0 >= v1);                       // tie -> h0 = lower index
        idxout[ob + j] = t0 ? ii[i0] : ii[16 + i1];
        if (t0) ++i0; else ++i1;
    }
}

// ----------------------------------------------- K3: P/Q precompute ---------
__global__ __launch_bounds__(256) void k_pq(const float* __restrict__ fea,
                                            const float* __restrict__ Wf1,
                                            const float* __restrict__ bf1,
                                            float* __restrict__ Pt,
                                            float* __restrict__ Qt) {
    __shared__ __align__(16) float feaT[64][64];    // [c][n]
    __shared__ __align__(16) float WT[64][132];     // [c][o'], o' in 0..127
    __shared__ float sb[64];

    const int b = blockIdx.y;
    const int n0 = blockIdx.x * 64;
    const int tid = threadIdx.x;
    const int to = tid & 15, tn = tid >> 4;
    const float* feab = fea + (size_t)b * NCH * NPTS;

#pragma unroll
    for (int i = 0; i < 4; ++i) {
        int e = i * 1024 + tid * 4;
        int c = e >> 6, nn = e & 63;
        *(float4*)&feaT[c][nn] = *(const float4*)&feab[c * NPTS + n0 + nn];
    }
#pragma unroll
    for (int i = 0; i < 8; ++i) {
        int g = tid * 32 + i * 4;
        int op = g >> 6, c = g & 63;
        const float* src = (op < 64) ? &Wf1[op * 128 + c]
                                     : &Wf1[(op - 64) * 128 + 64 + c];
        float4 w = *(const float4*)src;
        WT[c + 0][op] = w.x; WT[c + 1][op] = w.y;
        WT[c + 2][op] = w.z; WT[c + 3][op] = w.w;
    }
    if (tid < 64) sb[tid] = bf1[tid];
    __syncthreads();

    float acc[4][8];
#pragma unroll
    for (int ni = 0; ni < 4; ++ni)
#pragma unroll
        for (int oj = 0; oj < 8; ++oj) acc[ni][oj] = 0.f;

#pragma unroll 4
    for (int c = 0; c < 64; ++c) {
        float4 a  = *(const float4*)&feaT[c][tn * 4];
        float4 w0 = *(const float4*)&WT[c][to * 8];
        float4 w1 = *(const float4*)&WT[c][to * 8 + 4];
        float av[4] = {a.x, a.y, a.z, a.w};
        float wv[8] = {w0.x, w0.y, w0.z, w0.w, w1.x, w1.y, w1.z, w1.w};
#pragma unroll
        for (int ni = 0; ni < 4; ++ni)
#pragma unroll
            for (int oj = 0; oj < 8; ++oj)
                acc[ni][oj] = fmaf(av[ni], wv[oj], acc[ni][oj]);
    }

    const int opb = to * 8;
#pragma unroll
    for (int ni = 0; ni < 4; ++ni) {
        int n = n0 + tn * 4 + ni;
        size_t base = ((size_t)b * NPTS + n) * 64;
        if (opb < 64) {     // P half: add bias
            float4 o0, o1;
            o0.x = acc[ni][0] + sb[opb + 0]; o0.y = acc[ni][1] + sb[opb + 1];
            o0.z = acc[ni][2] + sb[opb + 2]; o0.w = acc[ni][3] + sb[opb + 3];
            o1.x = acc[ni][4] + sb[opb + 4]; o1.y = acc[ni][5] + sb[opb + 5];
            o1.z = acc[ni][6] + sb[opb + 6]; o1.w = acc[ni][7] + sb[opb + 7];
            *(float4*)&Pt[base + opb]     = o0;
            *(float4*)&Pt[base + opb + 4] = o1;
        } else {            // Q half: no bias
            float4 o0, o1;
            o0.x = acc[ni][0]; o0.y = acc[ni][1]; o0.z = acc[ni][2]; o0.w = acc[ni][3];
            o1.x = acc[ni][4]; o1.y = acc[ni][5]; o1.z = acc[ni][6]; o1.w = acc[ni][7];
            *(float4*)&Qt[base + opb - 64]     = o0;
            *(float4*)&Qt[base + opb - 64 + 4] = o1;
        }
    }
}

// -------------------------------------------- K4: fused MLP + max ----------
__global__ __launch_bounds__(256) void k_mlp(
    const float* __restrict__ xyz,
    const float* __restrict__ Pt, const float* __restrict__ Qt,
    const int* __restrict__ knnidx,
    const float* __restrict__ Wg1, const float* __restrict__ bg1,
    const float* __restrict__ Wg2, const float* __restrict__ bg2,
    const float* __restrict__ Wf2, const float* __restrict__ bf2,
    const float* __restrict__ Wf3, const float* __restrict__ bf3,
    float* __restrict__ out) {
    __shared__ __align__(16) float bufX[64][68];
    __shared__ __align__(16) float bufY[64][68];
    __shared__ __align__(16) float Wbuf[64][68];
    __shared__ __align__(16) float scratch[1280];  // geo[10][68] then pm[64][17]
    __shared__ float biasS[64];
    __shared__ int sidx[64];

    const int b = blockIdx.y;
    const int n0 = blockIdx.x * 4;
    const int tid = threadIdx.x;
    const int to = tid & 15, tp = tid >> 4;

    if (tid < 64)
        sidx[tid] = knnidx[((size_t)(b * NPTS + n0)) * KNN + tid];
    __syncthreads();

    // f1 = relu(P + Q_gather) into bufX [c][pair]
    {
        int pair = tid >> 2, q = tid & 3;
        int m = sidx[pair];
        int pt = pair >> 4;
        const float* pB = &Pt[((size_t)b * NPTS + n0 + pt) * 64];
        const float* qB = &Qt[((size_t)b * NPTS + m) * 64];
#pragma unroll
        for (int i = 0; i < 4; ++i) {
            int c0 = q * 16 + i * 4;
            float4 pv = *(const float4*)&pB[c0];
            float4 qv = *(const float4*)&qB[c0];
            bufX[c0 + 0][pair] = fmaxf(pv.x + qv.x, 0.f);
            bufX[c0 + 1][pair] = fmaxf(pv.y + qv.y, 0.f);
            bufX[c0 + 2][pair] = fmaxf(pv.z + qv.z, 0.f);
            bufX[c0 + 3][pair] = fmaxf(pv.w + qv.w, 0.f);
        }
    }
    // geo [10][68] into scratch
    if (tid < 64) {
        int pair = tid, pt = pair >> 4;
        int m = sidx[pair];
        const float* xb = xyz + (size_t)b * 3 * NPTS;
        float cx = xb[0 * NPTS + n0 + pt], cy = xb[1 * NPTS + n0 + pt], cz = xb[2 * NPTS + n0 + pt];
        float kx = xb[0 * NPTS + m], ky = xb[1 * NPTS + m], kz = xb[2 * NPTS + m];
        float rx = cx - kx, ry = cy - ky, rz = cz - kz;
        float d = sqrtf(rx * rx + ry * ry + rz * rz);
        scratch[0 * 68 + pair] = d;
        scratch[1 * 68 + pair] = cx; scratch[2 * 68 + pair] = cy; scratch[3 * 68 + pair] = cz;
        scratch[4 * 68 + pair] = kx; scratch[5 * 68 + pair] = ky; scratch[6 * 68 + pair] = kz;
        scratch[7 * 68 + pair] = rx; scratch[8 * 68 + pair] = ry; scratch[9 * 68 + pair] = rz;
    }

    auto stageW = [&](const float* W, const float* bv) {
#pragma unroll
        for (int i = 0; i < 4; ++i) {
            int g = tid * 16 + i * 4;
            int o = g >> 6, c = g & 63;
            float4 w = *(const float4*)&W[g];
            Wbuf[c + 0][o] = w.x; Wbuf[c + 1][o] = w.y;
            Wbuf[c + 2][o] = w.z; Wbuf[c + 3][o] = w.w;
        }
        if (tid < 64) biasS[tid] = bv[tid];
    };

    auto gemmPh = [&](const float* src, float* dst, int Kdim) {
        float acc[4][4] = {{0.f,0.f,0.f,0.f},{0.f,0.f,0.f,0.f},
                           {0.f,0.f,0.f,0.f},{0.f,0.f,0.f,0.f}};
#pragma unroll 2
        for (int c = 0; c < Kdim; ++c) {
            float4 w = *(const float4*)&Wbuf[c][to * 4];
            float4 a = *(const float4*)(src + c * 68 + tp * 4);
            float wr[4] = {w.x, w.y, w.z, w.w};
            float ar[4] = {a.x, a.y, a.z, a.w};
#pragma unroll
            for (int oi = 0; oi < 4; ++oi)
#pragma unroll
                for (int pj = 0; pj < 4; ++pj)
                    acc[oi][pj] = fmaf(wr[oi], ar[pj], acc[oi][pj]);
        }
#pragma unroll
        for (int oi = 0; oi < 4; ++oi) {
            float bo = biasS[to * 4 + oi];
            float4 o4;
            o4.x = fmaxf(acc[oi][0] + bo, 0.f);
            o4.y = fmaxf(acc[oi][1] + bo, 0.f);
            o4.z = fmaxf(acc[oi][2] + bo, 0.f);
            o4.w = fmaxf(acc[oi][3] + bo, 0.f);
            *(float4*)(dst + (to * 4 + oi) * 68 + tp * 4) = o4;
        }
    };

    stageW(Wf2, bf2);
    __syncthreads();
    gemmPh(&bufX[0][0], &bufY[0][0], 64);       // f2
    __syncthreads();
    stageW(Wf3, bf3);
    __syncthreads();
    gemmPh(&bufY[0][0], &bufX[0][0], 64);       // f3 -> bufX
    __syncthreads();
    {   // Wg1 is 64x10
        for (int e = tid; e < 640; e += 256) {
            int o = e / 10, c = e - o * 10;
            Wbuf[c][o] = Wg1[e];
        }
        if (tid < 64) biasS[tid] = bg1[tid];
    }
    __syncthreads();
    gemmPh(scratch, &bufY[0][0], 10);           // g1 -> bufY
    __syncthreads();
    stageW(Wg2, bg2);
    __syncthreads();
    {   // g2 GEMM with fused *f3 and partial max epilogue
        float acc[4][4] = {{0.f,0.f,0.f,0.f},{0.f,0.f,0.f,0.f},
                           {0.f,0.f,0.f,0.f},{0.f,0.f,0.f,0.f}};
#pragma unroll 2
        for (int c = 0; c < 64; ++c) {
            float4 w = *(const float4*)&Wbuf[c][to * 4];
            float4 a = *(const float4*)&bufY[c][tp * 4];
            float wr[4] = {w.x, w.y, w.z, w.w};
            float ar[4] = {a.x, a.y, a.z, a.w};
#pragma unroll
            for (int oi = 0; oi < 4; ++oi)
#pragma unroll
                for (int pj = 0; pj < 4; ++pj)
                    acc[oi][pj] = fmaf(wr[oi], ar[pj], acc[oi][pj]);
        }
#pragma unroll
        for (int oi = 0; oi < 4; ++oi) {
            int o = to * 4 + oi;
            float bo = biasS[o];
            float mx = -3.0e38f;
#pragma unroll
            for (int pj = 0; pj < 4; ++pj) {
                float g2v = fmaxf(acc[oi][pj] + bo, 0.f);
                float f3v = bufX[o][tp * 4 + pj];
                mx = fmaxf(mx, g2v * f3v);
            }
            scratch[o * 17 + tp] = mx;          // pm[64][17]
        }
    }
    __syncthreads();
    {
        int o = tid & 63, pt = tid >> 6;
        float m0_ = scratch[o * 17 + pt * 4 + 0];
        float m1  = scratch[o * 17 + pt * 4 + 1];
        float m2  = scratch[o * 17 + pt * 4 + 2];
        float m3  = scratch[o * 17 + pt * 4 + 3];
        out[((size_t)b * 64 + o) * NPTS + n0 + pt] =
            fmaxf(fmaxf(m0_, m1), fmaxf(m2, m3));
    }
}

// ---------------------------------------------------------------------------
extern "C" void kernel_launch(void* const* d_in, const int* in_sizes, int n_in,
                              void* d_out, int out_size, void* d_ws, size_t ws_size,
                              hipStream_t stream) {
    const float* xyz = (const float*)d_in[0];
    const float* fea = (const float*)d_in[1];
    const float* Wg1 = (const float*)d_in[2];
    const float* bg1 = (const float*)d_in[3];
    const float* Wg2 = (const float*)d_in[4];
    const float* bg2 = (const float*)d_in[5];
    const float* Wf1 = (const float*)d_in[6];
    const float* bf1 = (const float*)d_in[7];
    const float* Wf2 = (const float*)d_in[8];
    const float* bf2 = (const float*)d_in[9];
    const float* Wf3 = (const float*)d_in[10];
    const float* bf3 = (const float*)d_in[11];
    float* out = (float*)d_out;
    float* ws = (float*)d_ws;

    float* sq = ws + WS_SQ;
    float* Pt = ws + WS_PT;
    float* Qt = ws + WS_QT;
    int* idxw = (int*)(ws + WS_IDX);
    // vh/ih alias the Pt region (dead before k_pq writes Pt)
    float* vh = ws + WS_PT;
    int*   ih = (int*)(ws + WS_PT + NB * NPTS * 32);

    k_sq   <<<dim3(128),       dim3(256), 0, stream>>>(fea, sq);
    k_knn  <<<dim3(32, 2, 8),  dim3(256), 0, stream>>>(fea, sq, vh, ih);
    k_merge<<<dim3(128),       dim3(256), 0, stream>>>(vh, ih, idxw);
    k_pq   <<<dim3(64, 8),     dim3(256), 0, stream>>>(fea, Wf1, bf1, Pt, Qt);
    k_mlp  <<<dim3(1024, 8),   dim3(256), 0, stream>>>(xyz, Pt, Qt, idxw,
                                                       Wg1, bg1, Wg2, bg2,
                                                       Wf2, bf2, Wf3, bf3, out);
}

// Round 10
// 698.737 us; speedup vs baseline: 1.1357x; 1.1357x over previous
//
#include <hip/hip_runtime.h>
#include <math.h>

#define NB 8
#define NPTS 4096
#define NCH 64
#define NOUT 64
#define KNN 16
#define HALFC 2048

#define GLOBAL_AS const __attribute__((address_space(1)))
#define LDS_AS __attribute__((address_space(3)))

// ws layout in floats:
#define WS_SQ  0
#define WS_PT  (NB*NPTS)                       // 32768
#define WS_QT  (WS_PT + NB*NPTS*64)            // + 2097152
#define WS_IDX (WS_QT + NB*NPTS*64)            // int32 region, NB*NPTS*16 ints
// vh/ih (KNN halves' value/idx lists) ALIAS the Pt region: dead before k_pq.

// ---------------------------------------------------------------- K1: sq ----
__global__ __launch_bounds__(256) void k_sq(const float* __restrict__ fea,
                                            float* __restrict__ sq) {
    int g = blockIdx.x * 256 + threadIdx.x;      // 32768
    int b = g >> 12, n = g & 4095;
    const float* f = fea + (size_t)b * NCH * NPTS + n;
    float s = 0.f;
#pragma unroll
    for (int c = 0; c < NCH; ++c) s = fmaf(f[c * NPTS], f[c * NPTS], s);
    sq[g] = s;
}

// ------------------------------------------------------- K2: fused KNN ------
// r10: r8 machinery at 4-blocks/CU occupancy. 64-row panels x 64-col tiles
// (rowT 16KB + colT 16KB = 32KB -> 4 blocks/CU, 16 waves/CU, 4/SIMD to hide
// the scan's serial cross-lane chains). Grid 64x2x8 = 1024 = exact 4/CU fit.
// Wave owns 16 rows (4 groups x 4 rows); lane (g,p): acc[4][4] = rows
// rbase..+3, cols p*4..+3. Scan: ballot-filtered lockstep pops, DPP-shift
// insertion, persistent thr -- byte-identical logic to r8 (2 rounds proven).
// Staging: gram -> barrier -> issue global_load_lds(t+1) -> scan -> barrier
// (vmcnt drain) so HBM latency hides under the scan.
__global__ __launch_bounds__(256, 4) void k_knn(const float* __restrict__ fea,
                                                const float* __restrict__ sq,
                                                float* __restrict__ vh,
                                                int* __restrict__ ih) {
    __shared__ __align__(16) float rowT[64][64];    // 16KB [c][r]
    __shared__ __align__(16) float colT[64 * 64];   // 16KB [c][j]

    const int b = blockIdx.z;
    const int half = blockIdx.y;
    const int n0 = blockIdx.x * 64;
    const int cbase = half * HALFC;
    const int tid = threadIdx.x;
    const int lane = tid & 63, w = tid >> 6;
    const int g = lane >> 4, p = lane & 15;
    const int rbase = w * 16 + g * 4;               // this lane's 4 rows
    const float* feab = fea + (size_t)b * NCH * NPTS;

    // async stage of colT (64ch x 64 cols) for tile at m0; 4 insts/wave
    auto stage = [&](int m0) {
#pragma unroll
        for (int i = 0; i < 4; ++i) {
            int k = w * 4 + i;                      // chunk: 256 floats
            int c = 4 * k + (lane >> 4);
            int j = (lane & 15) * 4;
            const float* gp = feab + c * NPTS + m0 + j;
            float* lp = &colT[k * 256];             // wave-uniform base
            __builtin_amdgcn_global_load_lds((GLOBAL_AS void*)gp,
                                             (LDS_AS void*)lp, 16, 0, 0);
        }
    };

#pragma unroll
    for (int i = 0; i < 4; ++i) {
        int e = i * 1024 + tid * 4;
        int c = e >> 6, r = e & 63;
        *(float4*)&rowT[c][r] = *(const float4*)&feab[c * NPTS + n0 + r];
    }

    float lstv[4];                                  // row rbase+i list,
    int   lsti[4];                                  // lane p = p-th smallest
    float thr[4];                                   // group-uniform list min
#pragma unroll
    for (int i = 0; i < 4; ++i) {
        lstv[i] = -3.0e38f; lsti[i] = 0; thr[i] = -3.0e38f;
    }

    // insert (vv, col) into row-i list; group-uniform call; DPP shift-by-1
    auto ins = [&](int i, float vv, int col) {
        unsigned long long lt = __ballot(lstv[i] < vv);
        int pos = __popc((unsigned)((lt >> (g * 16)) & 0xFFFFu));
        int nv = __builtin_amdgcn_update_dpp(0, __float_as_int(lstv[i]),
                                             0x101, 0xF, 0xF, true);
        int ni = __builtin_amdgcn_update_dpp(0, lsti[i],
                                             0x101, 0xF, 0xF, true);
        if (p <= pos - 2)      { lstv[i] = __int_as_float(nv); lsti[i] = ni; }
        else if (p == pos - 1) { lstv[i] = vv; lsti[i] = col; }
    };

    stage(cbase);                                   // prologue: tile 0
    __syncthreads();                                // vmcnt drain + rowT ready

    for (int t = 0; t < 32; ++t) {
        const int m0 = cbase + t * 64;

        float4 sqc = *(const float4*)&sq[b * NPTS + m0 + p * 4];

        float acc[4][4] = {{0.f,0.f,0.f,0.f},{0.f,0.f,0.f,0.f},
                           {0.f,0.f,0.f,0.f},{0.f,0.f,0.f,0.f}};
#pragma unroll 8
        for (int c = 0; c < 64; ++c) {
            float4 rv = *(const float4*)&rowT[c][rbase];
            float4 cv = *(const float4*)&colT[c * 64 + p * 4];
            float rr[4] = {rv.x, rv.y, rv.z, rv.w};
            float cc[4] = {cv.x, cv.y, cv.z, cv.w};
#pragma unroll
            for (int ri = 0; ri < 4; ++ri)
#pragma unroll
                for (int ci = 0; ci < 4; ++ci)
                    acc[ri][ci] = fmaf(rr[ri], cc[ci], acc[ri][ci]);
        }

        __syncthreads();            // all waves done reading colT(t)
        if (t < 31) stage(m0 + 64); // issue t+1 loads; land during scan

        // transform: dist = 2*G - sq[col]
        float sqa[4] = {sqc.x, sqc.y, sqc.z, sqc.w};
#pragma unroll
        for (int i = 0; i < 4; ++i)
#pragma unroll
            for (int j = 0; j < 4; ++j)
                acc[i][j] = fmaf(2.f, acc[i][j], -sqa[j]);

        // ---- scan: 4 rows; lockstep pops across the 4 groups ----
#pragma unroll
        for (int i = 0; i < 4; ++i) {
            float v0 = acc[i][0], v1 = acc[i][1];
            float v2 = acc[i][2], v3 = acc[i][3];
            float vm = fmaxf(fmaxf(v0, v1), fmaxf(v2, v3));
            unsigned long long bal = __ballot(vm > thr[i]);
            unsigned mg = (unsigned)((bal >> (g * 16)) & 0xFFFFull);
            while (__any(mg != 0u)) {
                bool act = (mg != 0u);
                int srcp = act ? (__ffs(mg) - 1) : 0;
                mg &= (mg - 1u);                    // 0 stays 0
                int srcl = (g << 4) | srcp;
                float b0 = __shfl(v0, srcl);        // 4 parallel bcasts
                float b1 = __shfl(v1, srcl);
                float b2 = __shfl(v2, srcl);
                float b3 = __shfl(v3, srcl);
                if (act) {
                    int cb = m0 + srcp * 4;
                    if (b0 > thr[i]) ins(i, b0, cb + 0);
                    if (b1 > thr[i]) ins(i, b1, cb + 1);
                    if (b2 > thr[i]) ins(i, b2, cb + 2);
                    if (b3 > thr[i]) ins(i, b3, cb + 3);
                }
            }
            if (bal) thr[i] = __shfl(lstv[i], 0, 16);
        }
        // barrier: own-wave vmcnt drain completes stage(t+1); all waves'
        // ds-writes from global_load_lds are visible after it.
        __syncthreads();
    }

#pragma unroll
    for (int i = 0; i < 4; ++i) {                   // descending lists
        int row = rbase + i;
        size_t base = ((size_t)(b * NPTS) + n0 + row) * 32 + half * 16;
        vh[base + (15 - p)] = lstv[i];
        ih[base + (15 - p)] = lsti[i];
    }
}

// --------------------------------- K2b: merge the two half-range lists -----
__global__ __launch_bounds__(256) void k_merge(const float* __restrict__ vh,
                                               const int* __restrict__ ih,
                                               int* __restrict__ idxout) {
    int row = blockIdx.x * 256 + threadIdx.x;       // 32768 rows
    const float* v = vh + (size_t)row * 32;         // [0..15] h0, [16..31] h1
    const int* ii = ih + (size_t)row * 32;
    size_t ob = (size_t)row * KNN;
    int i0 = 0, i1 = 0;
#pragma unroll
    for (int j = 0; j < KNN; ++j) {
        float v0 = (i0 < 16) ? v[i0] : -3.4e38f;
        float v1 = (i1 < 16) ? v[16 + i1] : -3.4e38f;
        bool t0 = (v0 >= v1);                       // tie -> h0 = lower index
        idxout[ob + j] = t0 ? ii[i0] : ii[16 + i1];
        if (t0) ++i0; else ++i1;
    }
}

// ----------------------------------------------- K3: P/Q precompute ---------
__global__ __launch_bounds__(256) void k_pq(const float* __restrict__ fea,
                                            const float* __restrict__ Wf1,
                                            const float* __restrict__ bf1,
                                            float* __restrict__ Pt,
                                            float* __restrict__ Qt) {
    __shared__ __align__(16) float feaT[64][64];    // [c][n]
    __shared__ __align__(16) float WT[64][132];     // [c][o'], o' in 0..127
    __shared__ float sb[64];

    const int b = blockIdx.y;
    const int n0 = blockIdx.x * 64;
    const int tid = threadIdx.x;
    const int to = tid & 15, tn = tid >> 4;
    const float* feab = fea + (size_t)b * NCH * NPTS;

#pragma unroll
    for (int i = 0; i < 4; ++i) {
        int e = i * 1024 + tid * 4;
        int c = e >> 6, nn = e & 63;
        *(float4*)&feaT[c][nn] = *(const float4*)&feab[c * NPTS + n0 + nn];
    }
#pragma unroll
    for (int i = 0; i < 8; ++i) {
        int g = tid * 32 + i * 4;
        int op = g >> 6, c = g & 63;
        const float* src = (op < 64) ? &Wf1[op * 128 + c]
                                     : &Wf1[(op - 64) * 128 + 64 + c];
        float4 w = *(const float4*)src;
        WT[c + 0][op] = w.x; WT[c + 1][op] = w.y;
        WT[c + 2][op] = w.z; WT[c + 3][op] = w.w;
    }
    if (tid < 64) sb[tid] = bf1[tid];
    __syncthreads();

    float acc[4][8];
#pragma unroll
    for (int ni = 0; ni < 4; ++ni)
#pragma unroll
        for (int oj = 0; oj < 8; ++oj) acc[ni][oj] = 0.f;

#pragma unroll 4
    for (int c = 0; c < 64; ++c) {
        float4 a  = *(const float4*)&feaT[c][tn * 4];
        float4 w0 = *(const float4*)&WT[c][to * 8];
        float4 w1 = *(const float4*)&WT[c][to * 8 + 4];
        float av[4] = {a.x, a.y, a.z, a.w};
        float wv[8] = {w0.x, w0.y, w0.z, w0.w, w1.x, w1.y, w1.z, w1.w};
#pragma unroll
        for (int ni = 0; ni < 4; ++ni)
#pragma unroll
            for (int oj = 0; oj < 8; ++oj)
                acc[ni][oj] = fmaf(av[ni], wv[oj], acc[ni][oj]);
    }

    const int opb = to * 8;
#pragma unroll
    for (int ni = 0; ni < 4; ++ni) {
        int n = n0 + tn * 4 + ni;
        size_t base = ((size_t)b * NPTS + n) * 64;
        if (opb < 64) {     // P half: add bias
            float4 o0, o1;
            o0.x = acc[ni][0] + sb[opb + 0]; o0.y = acc[ni][1] + sb[opb + 1];
            o0.z = acc[ni][2] + sb[opb + 2]; o0.w = acc[ni][3] + sb[opb + 3];
            o1.x = acc[ni][4] + sb[opb + 4]; o1.y = acc[ni][5] + sb[opb + 5];
            o1.z = acc[ni][6] + sb[opb + 6]; o1.w = acc[ni][7] + sb[opb + 7];
            *(float4*)&Pt[base + opb]     = o0;
            *(float4*)&Pt[base + opb + 4] = o1;
        } else {            // Q half: no bias
            float4 o0, o1;
            o0.x = acc[ni][0]; o0.y = acc[ni][1]; o0.z = acc[ni][2]; o0.w = acc[ni][3];
            o1.x = acc[ni][4]; o1.y = acc[ni][5]; o1.z = acc[ni][6]; o1.w = acc[ni][7];
            *(float4*)&Qt[base + opb - 64]     = o0;
            *(float4*)&Qt[base + opb - 64 + 4] = o1;
        }
    }
}

// -------------------------------------------- K4: fused MLP + max ----------
__global__ __launch_bounds__(256) void k_mlp(
    const float* __restrict__ xyz,
    const float* __restrict__ Pt, const float* __restrict__ Qt,
    const int* __restrict__ knnidx,
    const float* __restrict__ Wg1, const float* __restrict__ bg1,
    const float* __restrict__ Wg2, const float* __restrict__ bg2,
    const float* __restrict__ Wf2, const float* __restrict__ bf2,
    const float* __restrict__ Wf3, const float* __restrict__ bf3,
    float* __restrict__ out) {
    __shared__ __align__(16) float bufX[64][68];
    __shared__ __align__(16) float bufY[64][68];
    __shared__ __align__(16) float Wbuf[64][68];
    __shared__ __align__(16) float scratch[1280];  // geo[10][68] then pm[64][17]
    __shared__ float biasS[64];
    __shared__ int sidx[64];

    const int b = blockIdx.y;
    const int n0 = blockIdx.x * 4;
    const int tid = threadIdx.x;
    const int to = tid & 15, tp = tid >> 4;

    if (tid < 64)
        sidx[tid] = knnidx[((size_t)(b * NPTS + n0)) * KNN + tid];
    __syncthreads();

    // f1 = relu(P + Q_gather) into bufX [c][pair]
    {
        int pair = tid >> 2, q = tid & 3;
        int m = sidx[pair];
        int pt = pair >> 4;
        const float* pB = &Pt[((size_t)b * NPTS + n0 + pt) * 64];
        const float* qB = &Qt[((size_t)b * NPTS + m) * 64];
#pragma unroll
        for (int i = 0; i < 4; ++i) {
            int c0 = q * 16 + i * 4;
            float4 pv = *(const float4*)&pB[c0];
            float4 qv = *(const float4*)&qB[c0];
            bufX[c0 + 0][pair] = fmaxf(pv.x + qv.x, 0.f);
            bufX[c0 + 1][pair] = fmaxf(pv.y + qv.y, 0.f);
            bufX[c0 + 2][pair] = fmaxf(pv.z + qv.z, 0.f);
            bufX[c0 + 3][pair] = fmaxf(pv.w + qv.w, 0.f);
        }
    }
    // geo [10][68] into scratch
    if (tid < 64) {
        int pair = tid, pt = pair >> 4;
        int m = sidx[pair];
        const float* xb = xyz + (size_t)b * 3 * NPTS;
        float cx = xb[0 * NPTS + n0 + pt], cy = xb[1 * NPTS + n0 + pt], cz = xb[2 * NPTS + n0 + pt];
        float kx = xb[0 * NPTS + m], ky = xb[1 * NPTS + m], kz = xb[2 * NPTS + m];
        float rx = cx - kx, ry = cy - ky, rz = cz - kz;
        float d = sqrtf(rx * rx + ry * ry + rz * rz);
        scratch[0 * 68 + pair] = d;
        scratch[1 * 68 + pair] = cx; scratch[2 * 68 + pair] = cy; scratch[3 * 68 + pair] = cz;
        scratch[4 * 68 + pair] = kx; scratch[5 * 68 + pair] = ky; scratch[6 * 68 + pair] = kz;
        scratch[7 * 68 + pair] = rx; scratch[8 * 68 + pair] = ry; scratch[9 * 68 + pair] = rz;
    }

    auto stageW = [&](const float* W, const float* bv) {
#pragma unroll
        for (int i = 0; i < 4; ++i) {
            int g = tid * 16 + i * 4;
            int o = g >> 6, c = g & 63;
            float4 w = *(const float4*)&W[g];
            Wbuf[c + 0][o] = w.x; Wbuf[c + 1][o] = w.y;
            Wbuf[c + 2][o] = w.z; Wbuf[c + 3][o] = w.w;
        }
        if (tid < 64) biasS[tid] = bv[tid];
    };

    auto gemmPh = [&](const float* src, float* dst, int Kdim) {
        float acc[4][4] = {{0.f,0.f,0.f,0.f},{0.f,0.f,0.f,0.f},
                           {0.f,0.f,0.f,0.f},{0.f,0.f,0.f,0.f}};
#pragma unroll 2
        for (int c = 0; c < Kdim; ++c) {
            float4 w = *(const float4*)&Wbuf[c][to * 4];
            float4 a = *(const float4*)(src + c * 68 + tp * 4);
            float wr[4] = {w.x, w.y, w.z, w.w};
            float ar[4] = {a.x, a.y, a.z, a.w};
#pragma unroll
            for (int oi = 0; oi < 4; ++oi)
#pragma unroll
                for (int pj = 0; pj < 4; ++pj)
                    acc[oi][pj] = fmaf(wr[oi], ar[pj], acc[oi][pj]);
        }
#pragma unroll
        for (int oi = 0; oi < 4; ++oi) {
            float bo = biasS[to * 4 + oi];
            float4 o4;
            o4.x = fmaxf(acc[oi][0] + bo, 0.f);
            o4.y = fmaxf(acc[oi][1] + bo, 0.f);
            o4.z = fmaxf(acc[oi][2] + bo, 0.f);
            o4.w = fmaxf(acc[oi][3] + bo, 0.f);
            *(float4*)(dst + (to * 4 + oi) * 68 + tp * 4) = o4;
        }
    };

    stageW(Wf2, bf2);
    __syncthreads();
    gemmPh(&bufX[0][0], &bufY[0][0], 64);       // f2
    __syncthreads();
    stageW(Wf3, bf3);
    __syncthreads();
    gemmPh(&bufY[0][0], &bufX[0][0], 64);       // f3 -> bufX
    __syncthreads();
    {   // Wg1 is 64x10
        for (int e = tid; e < 640; e += 256) {
            int o = e / 10, c = e - o * 10;
            Wbuf[c][o] = Wg1[e];
        }
        if (tid < 64) biasS[tid] = bg1[tid];
    }
    __syncthreads();
    gemmPh(scratch, &bufY[0][0], 10);           // g1 -> bufY
    __syncthreads();
    stageW(Wg2, bg2);
    __syncthreads();
    {   // g2 GEMM with fused *f3 and partial max epilogue
        float acc[4][4] = {{0.f,0.f,0.f,0.f},{0.f,0.f,0.f,0.f},
                           {0.f,0.f,0.f,0.f},{0.f,0.f,0.f,0.f}};
#pragma unroll 2
        for (int c = 0; c < 64; ++c) {
            float4 w = *(const float4*)&Wbuf[c][to * 4];
            float4 a = *(const float4*)&bufY[c][tp * 4];
            float wr[4] = {w.x, w.y, w.z, w.w};
            float ar[4] = {a.x, a.y, a.z, a.w};
#pragma unroll
            for (int oi = 0; oi < 4; ++oi)
#pragma unroll
                for (int pj = 0; pj < 4; ++pj)
                    acc[oi][pj] = fmaf(wr[oi], ar[pj], acc[oi][pj]);
        }
#pragma unroll
        for (int oi = 0; oi < 4; ++oi) {
            int o = to * 4 + oi;
            float bo = biasS[o];
            float mx = -3.0e38f;
#pragma unroll
            for (int pj = 0; pj < 4; ++pj) {
                float g2v = fmaxf(acc[oi][pj] + bo, 0.f);
                float f3v = bufX[o][tp * 4 + pj];
                mx = fmaxf(mx, g2v * f3v);
            }
            scratch[o * 17 + tp] = mx;          // pm[64][17]
        }
    }
    __syncthreads();
    {
        int o = tid & 63, pt = tid >> 6;
        float m0_ = scratch[o * 17 + pt * 4 + 0];
        float m1  = scratch[o * 17 + pt * 4 + 1];
        float m2  = scratch[o * 17 + pt * 4 + 2];
        float m3  = scratch[o * 17 + pt * 4 + 3];
        out[((size_t)b * 64 + o) * NPTS + n0 + pt] =
            fmaxf(fmaxf(m0_, m1), fmaxf(m2, m3));
    }
}

// ---------------------------------------------------------------------------
extern "C" void kernel_launch(void* const* d_in, const int* in_sizes, int n_in,
                              void* d_out, int out_size, void* d_ws, size_t ws_size,
                              hipStream_t stream) {
    const float* xyz = (const float*)d_in[0];
    const float* fea = (const float*)d_in[1];
    const float* Wg1 = (const float*)d_in[2];
    const float* bg1 = (const float*)d_in[3];
    const float* Wg2 = (const float*)d_in[4];
    const float* bg2 = (const float*)d_in[5];
    const float* Wf1 = (const float*)d_in[6];
    const float* bf1 = (const float*)d_in[7];
    const float* Wf2 = (const float*)d_in[8];
    const float* bf2 = (const float*)d_in[9];
    const float* Wf3 = (const float*)d_in[10];
    const float* bf3 = (const float*)d_in[11];
    float* out = (float*)d_out;
    float* ws = (float*)d_ws;

    float* sq = ws + WS_SQ;
    float* Pt = ws + WS_PT;
    float* Qt = ws + WS_QT;
    int* idxw = (int*)(ws + WS_IDX);
    // vh/ih alias the Pt region (dead before k_pq writes Pt)
    float* vh = ws + WS_PT;
    int*   ih = (int*)(ws + WS_PT + NB * NPTS * 32);

    k_sq   <<<dim3(128),       dim3(256), 0, stream>>>(fea, sq);
    k_knn  <<<dim3(64, 2, 8),  dim3(256), 0, stream>>>(fea, sq, vh, ih);
    k_merge<<<dim3(128),       dim3(256), 0, stream>>>(vh, ih, idxw);
    k_pq   <<<dim3(64, 8),     dim3(256), 0, stream>>>(fea, Wf1, bf1, Pt, Qt);
    k_mlp  <<<dim3(1024, 8),   dim3(256), 0, stream>>>(xyz, Pt, Qt, idxw,
                                                       Wg1, bg1, Wg2, bg2,
                                                       Wf2, bf2, Wf3, bf3, out);
}

// Round 11
// 673.495 us; speedup vs baseline: 1.1783x; 1.0375x over previous
//
#include <hip/hip_runtime.h>
#include <math.h>

#define NB 8
#define NPTS 4096
#define NCH 64
#define NOUT 64
#define KNN 16

#define GLOBAL_AS const __attribute__((address_space(1)))
#define LDS_AS __attribute__((address_space(3)))

// ws layout in floats:
#define WS_SQ  0
#define WS_PT  (NB*NPTS)                       // 32768
#define WS_QT  (WS_PT + NB*NPTS*64)            // + 2097152
#define WS_IDX (WS_QT + NB*NPTS*64)            // int32 region, NB*NPTS*16 ints

// ---------------------------------------------------------------- K1: sq ----
__global__ __launch_bounds__(256) void k_sq(const float* __restrict__ fea,
                                            float* __restrict__ sq) {
    int g = blockIdx.x * 256 + threadIdx.x;      // 32768
    int b = g >> 12, n = g & 4095;
    const float* f = fea + (size_t)b * NCH * NPTS + n;
    float s = 0.f;
#pragma unroll
    for (int c = 0; c < NCH; ++c) s = fmaf(f[c * NPTS], f[c * NPTS], s);
    sq[g] = s;
}

// ------------------------------------------------------- K2: fused KNN ------
// r11: single FULL-RANGE top-16 list per row (no halves, no merge kernel).
// Insert count per row drops 168 -> ~95 (16·ln(N/16)+16 scaling) and the
// k_merge pass disappears. Grid size restored via 32-row panels:
// grid 128x8 = 1024 = exact 4 blocks/CU (16 waves/CU, 4/SIMD). Wave owns
// 8 rows (2 per 16-lane group); lane (g,p): acc[2][4] = rows rbase..+1,
// cols p*4..+3. LDS 24KB (rowT 8K + colT 16K). Scan/ins/staging machinery
// byte-identical to r10 (3 rounds proven): ballot-filtered lockstep pops,
// DPP-shift insertion, persistent thr, global_load_lds staging of t+1
// issued after the gram barrier so HBM latency hides under the scan.
__global__ __launch_bounds__(256, 4) void k_knn(const float* __restrict__ fea,
                                                const float* __restrict__ sq,
                                                int* __restrict__ idxout) {
    __shared__ __align__(16) float rowT[64][32];    // 8KB  [c][r]
    __shared__ __align__(16) float colT[64 * 64];   // 16KB [c][j]

    const int b = blockIdx.y;
    const int n0 = blockIdx.x * 32;
    const int tid = threadIdx.x;
    const int lane = tid & 63, w = tid >> 6;
    const int g = lane >> 4, p = lane & 15;
    const int rbase = w * 8 + g * 2;                // this lane's 2 rows
    const float* feab = fea + (size_t)b * NCH * NPTS;

    // async stage of colT (64ch x 64 cols) for tile at m0; 4 insts/wave
    auto stage = [&](int m0) {
#pragma unroll
        for (int i = 0; i < 4; ++i) {
            int k = w * 4 + i;                      // chunk: 256 floats
            int c = 4 * k + (lane >> 4);
            int j = (lane & 15) * 4;
            const float* gp = feab + c * NPTS + m0 + j;
            float* lp = &colT[k * 256];             // wave-uniform base
            __builtin_amdgcn_global_load_lds((GLOBAL_AS void*)gp,
                                             (LDS_AS void*)lp, 16, 0, 0);
        }
    };

#pragma unroll
    for (int i = 0; i < 2; ++i) {                   // rowT: 64ch x 32 rows
        int e = i * 1024 + tid * 4;
        int c = e >> 5, r = e & 31;
        *(float4*)&rowT[c][r] = *(const float4*)&feab[c * NPTS + n0 + r];
    }

    float lstv[2];                                  // row rbase+i list,
    int   lsti[2];                                  // lane p = p-th smallest
    float thr[2];                                   // group-uniform list min
#pragma unroll
    for (int i = 0; i < 2; ++i) {
        lstv[i] = -3.0e38f; lsti[i] = 0; thr[i] = -3.0e38f;
    }

    // insert (vv, col) into row-i list; group-uniform call; DPP shift-by-1
    auto ins = [&](int i, float vv, int col) {
        unsigned long long lt = __ballot(lstv[i] < vv);
        int pos = __popc((unsigned)((lt >> (g * 16)) & 0xFFFFu));
        int nv = __builtin_amdgcn_update_dpp(0, __float_as_int(lstv[i]),
                                             0x101, 0xF, 0xF, true);
        int ni = __builtin_amdgcn_update_dpp(0, lsti[i],
                                             0x101, 0xF, 0xF, true);
        if (p <= pos - 2)      { lstv[i] = __int_as_float(nv); lsti[i] = ni; }
        else if (p == pos - 1) { lstv[i] = vv; lsti[i] = col; }
    };

    stage(0);                                       // prologue: tile 0
    __syncthreads();                                // vmcnt drain + rowT ready

    for (int t = 0; t < 64; ++t) {
        const int m0 = t * 64;

        float4 sqc = *(const float4*)&sq[b * NPTS + m0 + p * 4];

        float acc[2][4] = {{0.f,0.f,0.f,0.f},{0.f,0.f,0.f,0.f}};
#pragma unroll 8
        for (int c = 0; c < 64; ++c) {
            float2 rv = *(const float2*)&rowT[c][rbase];
            float4 cv = *(const float4*)&colT[c * 64 + p * 4];
            float cc[4] = {cv.x, cv.y, cv.z, cv.w};
#pragma unroll
            for (int ci = 0; ci < 4; ++ci) {
                acc[0][ci] = fmaf(rv.x, cc[ci], acc[0][ci]);
                acc[1][ci] = fmaf(rv.y, cc[ci], acc[1][ci]);
            }
        }

        __syncthreads();            // all waves done reading colT(t)
        if (t < 63) stage(m0 + 64); // issue t+1 loads; land during scan

        // transform: dist = 2*G - sq[col]
        float sqa[4] = {sqc.x, sqc.y, sqc.z, sqc.w};
#pragma unroll
        for (int i = 0; i < 2; ++i)
#pragma unroll
            for (int j = 0; j < 4; ++j)
                acc[i][j] = fmaf(2.f, acc[i][j], -sqa[j]);

        // ---- scan: 2 rows; lockstep pops across the 4 groups ----
#pragma unroll
        for (int i = 0; i < 2; ++i) {
            float v0 = acc[i][0], v1 = acc[i][1];
            float v2 = acc[i][2], v3 = acc[i][3];
            float vm = fmaxf(fmaxf(v0, v1), fmaxf(v2, v3));
            unsigned long long bal = __ballot(vm > thr[i]);
            unsigned mg = (unsigned)((bal >> (g * 16)) & 0xFFFFull);
            while (__any(mg != 0u)) {
                bool act = (mg != 0u);
                int srcp = act ? (__ffs(mg) - 1) : 0;
                mg &= (mg - 1u);                    // 0 stays 0
                int srcl = (g << 4) | srcp;
                float b0 = __shfl(v0, srcl);        // 4 parallel bcasts
                float b1 = __shfl(v1, srcl);
                float b2 = __shfl(v2, srcl);
                float b3 = __shfl(v3, srcl);
                if (act) {
                    int cb = m0 + srcp * 4;
                    if (b0 > thr[i]) ins(i, b0, cb + 0);
                    if (b1 > thr[i]) ins(i, b1, cb + 1);
                    if (b2 > thr[i]) ins(i, b2, cb + 2);
                    if (b3 > thr[i]) ins(i, b3, cb + 3);
                }
            }
            if (bal) thr[i] = __shfl(lstv[i], 0, 16);
        }
        // barrier: own-wave vmcnt drain completes stage(t+1); all waves'
        // ds-writes from global_load_lds are visible after it.
        __syncthreads();
    }

#pragma unroll
    for (int i = 0; i < 2; ++i) {                   // descending output
        int row = rbase + i;
        idxout[((size_t)(b * NPTS) + n0 + row) * KNN + (15 - p)] = lsti[i];
    }
}

// ----------------------------------------------- K3: P/Q precompute ---------
__global__ __launch_bounds__(256) void k_pq(const float* __restrict__ fea,
                                            const float* __restrict__ Wf1,
                                            const float* __restrict__ bf1,
                                            float* __restrict__ Pt,
                                            float* __restrict__ Qt) {
    __shared__ __align__(16) float feaT[64][64];    // [c][n]
    __shared__ __align__(16) float WT[64][132];     // [c][o'], o' in 0..127
    __shared__ float sb[64];

    const int b = blockIdx.y;
    const int n0 = blockIdx.x * 64;
    const int tid = threadIdx.x;
    const int to = tid & 15, tn = tid >> 4;
    const float* feab = fea + (size_t)b * NCH * NPTS;

#pragma unroll
    for (int i = 0; i < 4; ++i) {
        int e = i * 1024 + tid * 4;
        int c = e >> 6, nn = e & 63;
        *(float4*)&feaT[c][nn] = *(const float4*)&feab[c * NPTS + n0 + nn];
    }
#pragma unroll
    for (int i = 0; i < 8; ++i) {
        int g = tid * 32 + i * 4;
        int op = g >> 6, c = g & 63;
        const float* src = (op < 64) ? &Wf1[op * 128 + c]
                                     : &Wf1[(op - 64) * 128 + 64 + c];
        float4 w = *(const float4*)src;
        WT[c + 0][op] = w.x; WT[c + 1][op] = w.y;
        WT[c + 2][op] = w.z; WT[c + 3][op] = w.w;
    }
    if (tid < 64) sb[tid] = bf1[tid];
    __syncthreads();

    float acc[4][8];
#pragma unroll
    for (int ni = 0; ni < 4; ++ni)
#pragma unroll
        for (int oj = 0; oj < 8; ++oj) acc[ni][oj] = 0.f;

#pragma unroll 4
    for (int c = 0; c < 64; ++c) {
        float4 a  = *(const float4*)&feaT[c][tn * 4];
        float4 w0 = *(const float4*)&WT[c][to * 8];
        float4 w1 = *(const float4*)&WT[c][to * 8 + 4];
        float av[4] = {a.x, a.y, a.z, a.w};
        float wv[8] = {w0.x, w0.y, w0.z, w0.w, w1.x, w1.y, w1.z, w1.w};
#pragma unroll
        for (int ni = 0; ni < 4; ++ni)
#pragma unroll
            for (int oj = 0; oj < 8; ++oj)
                acc[ni][oj] = fmaf(av[ni], wv[oj], acc[ni][oj]);
    }

    const int opb = to * 8;
#pragma unroll
    for (int ni = 0; ni < 4; ++ni) {
        int n = n0 + tn * 4 + ni;
        size_t base = ((size_t)b * NPTS + n) * 64;
        if (opb < 64) {     // P half: add bias
            float4 o0, o1;
            o0.x = acc[ni][0] + sb[opb + 0]; o0.y = acc[ni][1] + sb[opb + 1];
            o0.z = acc[ni][2] + sb[opb + 2]; o0.w = acc[ni][3] + sb[opb + 3];
            o1.x = acc[ni][4] + sb[opb + 4]; o1.y = acc[ni][5] + sb[opb + 5];
            o1.z = acc[ni][6] + sb[opb + 6]; o1.w = acc[ni][7] + sb[opb + 7];
            *(float4*)&Pt[base + opb]     = o0;
            *(float4*)&Pt[base + opb + 4] = o1;
        } else {            // Q half: no bias
            float4 o0, o1;
            o0.x = acc[ni][0]; o0.y = acc[ni][1]; o0.z = acc[ni][2]; o0.w = acc[ni][3];
            o1.x = acc[ni][4]; o1.y = acc[ni][5]; o1.z = acc[ni][6]; o1.w = acc[ni][7];
            *(float4*)&Qt[base + opb - 64]     = o0;
            *(float4*)&Qt[base + opb - 64 + 4] = o1;
        }
    }
}

// -------------------------------------------- K4: fused MLP + max ----------
__global__ __launch_bounds__(256) void k_mlp(
    const float* __restrict__ xyz,
    const float* __restrict__ Pt, const float* __restrict__ Qt,
    const int* __restrict__ knnidx,
    const float* __restrict__ Wg1, const float* __restrict__ bg1,
    const float* __restrict__ Wg2, const float* __restrict__ bg2,
    const float* __restrict__ Wf2, const float* __restrict__ bf2,
    const float* __restrict__ Wf3, const float* __restrict__ bf3,
    float* __restrict__ out) {
    __shared__ __align__(16) float bufX[64][68];
    __shared__ __align__(16) float bufY[64][68];
    __shared__ __align__(16) float Wbuf[64][68];
    __shared__ __align__(16) float scratch[1280];  // geo[10][68] then pm[64][17]
    __shared__ float biasS[64];
    __shared__ int sidx[64];

    const int b = blockIdx.y;
    const int n0 = blockIdx.x * 4;
    const int tid = threadIdx.x;
    const int to = tid & 15, tp = tid >> 4;

    if (tid < 64)
        sidx[tid] = knnidx[((size_t)(b * NPTS + n0)) * KNN + tid];
    __syncthreads();

    // f1 = relu(P + Q_gather) into bufX [c][pair]
    {
        int pair = tid >> 2, q = tid & 3;
        int m = sidx[pair];
        int pt = pair >> 4;
        const float* pB = &Pt[((size_t)b * NPTS + n0 + pt) * 64];
        const float* qB = &Qt[((size_t)b * NPTS + m) * 64];
#pragma unroll
        for (int i = 0; i < 4; ++i) {
            int c0 = q * 16 + i * 4;
            float4 pv = *(const float4*)&pB[c0];
            float4 qv = *(const float4*)&qB[c0];
            bufX[c0 + 0][pair] = fmaxf(pv.x + qv.x, 0.f);
            bufX[c0 + 1][pair] = fmaxf(pv.y + qv.y, 0.f);
            bufX[c0 + 2][pair] = fmaxf(pv.z + qv.z, 0.f);
            bufX[c0 + 3][pair] = fmaxf(pv.w + qv.w, 0.f);
        }
    }
    // geo [10][68] into scratch
    if (tid < 64) {
        int pair = tid, pt = pair >> 4;
        int m = sidx[pair];
        const float* xb = xyz + (size_t)b * 3 * NPTS;
        float cx = xb[0 * NPTS + n0 + pt], cy = xb[1 * NPTS + n0 + pt], cz = xb[2 * NPTS + n0 + pt];
        float kx = xb[0 * NPTS + m], ky = xb[1 * NPTS + m], kz = xb[2 * NPTS + m];
        float rx = cx - kx, ry = cy - ky, rz = cz - kz;
        float d = sqrtf(rx * rx + ry * ry + rz * rz);
        scratch[0 * 68 + pair] = d;
        scratch[1 * 68 + pair] = cx; scratch[2 * 68 + pair] = cy; scratch[3 * 68 + pair] = cz;
        scratch[4 * 68 + pair] = kx; scratch[5 * 68 + pair] = ky; scratch[6 * 68 + pair] = kz;
        scratch[7 * 68 + pair] = rx; scratch[8 * 68 + pair] = ry; scratch[9 * 68 + pair] = rz;
    }

    auto stageW = [&](const float* W, const float* bv) {
#pragma unroll
        for (int i = 0; i < 4; ++i) {
            int g = tid * 16 + i * 4;
            int o = g >> 6, c = g & 63;
            float4 w = *(const float4*)&W[g];
            Wbuf[c + 0][o] = w.x; Wbuf[c + 1][o] = w.y;
            Wbuf[c + 2][o] = w.z; Wbuf[c + 3][o] = w.w;
        }
        if (tid < 64) biasS[tid] = bv[tid];
    };

    auto gemmPh = [&](const float* src, float* dst, int Kdim) {
        float acc[4][4] = {{0.f,0.f,0.f,0.f},{0.f,0.f,0.f,0.f},
                           {0.f,0.f,0.f,0.f},{0.f,0.f,0.f,0.f}};
#pragma unroll 2
        for (int c = 0; c < Kdim; ++c) {
            float4 w = *(const float4*)&Wbuf[c][to * 4];
            float4 a = *(const float4*)(src + c * 68 + tp * 4);
            float wr[4] = {w.x, w.y, w.z, w.w};
            float ar[4] = {a.x, a.y, a.z, a.w};
#pragma unroll
            for (int oi = 0; oi < 4; ++oi)
#pragma unroll
                for (int pj = 0; pj < 4; ++pj)
                    acc[oi][pj] = fmaf(wr[oi], ar[pj], acc[oi][pj]);
        }
#pragma unroll
        for (int oi = 0; oi < 4; ++oi) {
            float bo = biasS[to * 4 + oi];
            float4 o4;
            o4.x = fmaxf(acc[oi][0] + bo, 0.f);
            o4.y = fmaxf(acc[oi][1] + bo, 0.f);
            o4.z = fmaxf(acc[oi][2] + bo, 0.f);
            o4.w = fmaxf(acc[oi][3] + bo, 0.f);
            *(float4*)(dst + (to * 4 + oi) * 68 + tp * 4) = o4;
        }
    };

    stageW(Wf2, bf2);
    __syncthreads();
    gemmPh(&bufX[0][0], &bufY[0][0], 64);       // f2
    __syncthreads();
    stageW(Wf3, bf3);
    __syncthreads();
    gemmPh(&bufY[0][0], &bufX[0][0], 64);       // f3 -> bufX
    __syncthreads();
    {   // Wg1 is 64x10
        for (int e = tid; e < 640; e += 256) {
            int o = e / 10, c = e - o * 10;
            Wbuf[c][o] = Wg1[e];
        }
        if (tid < 64) biasS[tid] = bg1[tid];
    }
    __syncthreads();
    gemmPh(scratch, &bufY[0][0], 10);           // g1 -> bufY
    __syncthreads();
    stageW(Wg2, bg2);
    __syncthreads();
    {   // g2 GEMM with fused *f3 and partial max epilogue
        float acc[4][4] = {{0.f,0.f,0.f,0.f},{0.f,0.f,0.f,0.f},
                           {0.f,0.f,0.f,0.f},{0.f,0.f,0.f,0.f}};
#pragma unroll 2
        for (int c = 0; c < 64; ++c) {
            float4 w = *(const float4*)&Wbuf[c][to * 4];
            float4 a = *(const float4*)&bufY[c][tp * 4];
            float wr[4] = {w.x, w.y, w.z, w.w};
            float ar[4] = {a.x, a.y, a.z, a.w};
#pragma unroll
            for (int oi = 0; oi < 4; ++oi)
#pragma unroll
                for (int pj = 0; pj < 4; ++pj)
                    acc[oi][pj] = fmaf(wr[oi], ar[pj], acc[oi][pj]);
        }
#pragma unroll
        for (int oi = 0; oi < 4; ++oi) {
            int o = to * 4 + oi;
            float bo = biasS[o];
            float mx = -3.0e38f;
#pragma unroll
            for (int pj = 0; pj < 4; ++pj) {
                float g2v = fmaxf(acc[oi][pj] + bo, 0.f);
                float f3v = bufX[o][tp * 4 + pj];
                mx = fmaxf(mx, g2v * f3v);
            }
            scratch[o * 17 + tp] = mx;          // pm[64][17]
        }
    }
    __syncthreads();
    {
        int o = tid & 63, pt = tid >> 6;
        float m0_ = scratch[o * 17 + pt * 4 + 0];
        float m1  = scratch[o * 17 + pt * 4 + 1];
        float m2  = scratch[o * 17 + pt * 4 + 2];
        float m3  = scratch[o * 17 + pt * 4 + 3];
        out[((size_t)b * 64 + o) * NPTS + n0 + pt] =
            fmaxf(fmaxf(m0_, m1), fmaxf(m2, m3));
    }
}

// ---------------------------------------------------------------------------
extern "C" void kernel_launch(void* const* d_in, const int* in_sizes, int n_in,
                              void* d_out, int out_size, void* d_ws, size_t ws_size,
                              hipStream_t stream) {
    const float* xyz = (const float*)d_in[0];
    const float* fea = (const float*)d_in[1];
    const float* Wg1 = (const float*)d_in[2];
    const float* bg1 = (const float*)d_in[3];
    const float* Wg2 = (const float*)d_in[4];
    const float* bg2 = (const float*)d_in[5];
    const float* Wf1 = (const float*)d_in[6];
    const float* bf1 = (const float*)d_in[7];
    const float* Wf2 = (const float*)d_in[8];
    const float* bf2 = (const float*)d_in[9];
    const float* Wf3 = (const float*)d_in[10];
    const float* bf3 = (const float*)d_in[11];
    float* out = (float*)d_out;
    float* ws = (float*)d_ws;

    float* sq = ws + WS_SQ;
    float* Pt = ws + WS_PT;
    float* Qt = ws + WS_QT;
    int* idxw = (int*)(ws + WS_IDX);

    k_sq  <<<dim3(128),      dim3(256), 0, stream>>>(fea, sq);
    k_knn <<<dim3(128, 8),   dim3(256), 0, stream>>>(fea, sq, idxw);
    k_pq  <<<dim3(64, 8),    dim3(256), 0, stream>>>(fea, Wf1, bf1, Pt, Qt);
    k_mlp <<<dim3(1024, 8),  dim3(256), 0, stream>>>(xyz, Pt, Qt, idxw,
                                                     Wg1, bg1, Wg2, bg2,
                                                     Wf2, bf2, Wf3, bf3, out);
}

// Round 12
// 658.049 us; speedup vs baseline: 1.2059x; 1.0235x over previous
//
#include <hip/hip_runtime.h>
#include <math.h>

#define NB 8
#define NPTS 4096
#define NCH 64
#define NOUT 64
#define KNN 16

#define GLOBAL_AS const __attribute__((address_space(1)))
#define LDS_AS __attribute__((address_space(3)))

// ws layout in floats:
#define WS_SQ  0
#define WS_PT  (NB*NPTS)                       // 32768
#define WS_QT  (WS_PT + NB*NPTS*64)            // + 2097152
#define WS_IDX (WS_QT + NB*NPTS*64)            // int32 region, NB*NPTS*16 ints

// ---------------------------------------------------------------- K1: sq ----
__global__ __launch_bounds__(256) void k_sq(const float* __restrict__ fea,
                                            float* __restrict__ sq) {
    int g = blockIdx.x * 256 + threadIdx.x;      // 32768
    int b = g >> 12, n = g & 4095;
    const float* f = fea + (size_t)b * NCH * NPTS + n;
    float s = 0.f;
#pragma unroll
    for (int c = 0; c < NCH; ++c) s = fmaf(f[c * NPTS], f[c * NPTS], s);
    sq[g] = s;
}

// ------------------------------------------------------- K2: fused KNN ------
// r12: r11 (32-row panels, single full-range top-16 list, acc[2][4],
// DPP-shift insertion, 4 blocks/CU) + DOUBLE-BUFFERED colT -> ONE barrier
// per tile (64 vs r11's 128). stage(buf^1, t+1) is issued BEFORE the gram:
// buf^1 was last read in tile t-1, and the t-1 end barrier guarantees all
// waves are past it, so the write is race-free. The end-of-tile
// __syncthreads() drains own vmcnt (completing the prefetch) and makes all
// waves' global_load_lds writes visible -- the only barrier needed.
// LDS = rowT 8K + 2x16K colT = 40KB -> 4 blocks/CU at grid 128x8=1024.
__global__ __launch_bounds__(256, 4) void k_knn(const float* __restrict__ fea,
                                                const float* __restrict__ sq,
                                                int* __restrict__ idxout) {
    __shared__ __align__(16) float rowT[64][32];     // 8KB  [c][r]
    __shared__ __align__(16) float colT[2][64 * 64]; // 32KB [c][j] dbuf

    const int b = blockIdx.y;
    const int n0 = blockIdx.x * 32;
    const int tid = threadIdx.x;
    const int lane = tid & 63, w = tid >> 6;
    const int g = lane >> 4, p = lane & 15;
    const int rbase = w * 8 + g * 2;                // this lane's 2 rows
    const float* feab = fea + (size_t)b * NCH * NPTS;

    // async stage of colT[buf] (64ch x 64 cols) for tile at m0; 4 insts/wave
    auto stage = [&](int buf, int m0) {
#pragma unroll
        for (int i = 0; i < 4; ++i) {
            int k = w * 4 + i;                      // chunk: 256 floats
            int c = 4 * k + (lane >> 4);
            int j = (lane & 15) * 4;
            const float* gp = feab + c * NPTS + m0 + j;
            float* lp = &colT[buf][k * 256];        // wave-uniform base
            __builtin_amdgcn_global_load_lds((GLOBAL_AS void*)gp,
                                             (LDS_AS void*)lp, 16, 0, 0);
        }
    };

#pragma unroll
    for (int i = 0; i < 2; ++i) {                   // rowT: 64ch x 32 rows
        int e = i * 1024 + tid * 4;
        int c = e >> 5, r = e & 31;
        *(float4*)&rowT[c][r] = *(const float4*)&feab[c * NPTS + n0 + r];
    }

    float lstv[2];                                  // row rbase+i list,
    int   lsti[2];                                  // lane p = p-th smallest
    float thr[2];                                   // group-uniform list min
#pragma unroll
    for (int i = 0; i < 2; ++i) {
        lstv[i] = -3.0e38f; lsti[i] = 0; thr[i] = -3.0e38f;
    }

    // insert (vv, col) into row-i list; group-uniform call; DPP shift-by-1
    auto ins = [&](int i, float vv, int col) {
        unsigned long long lt = __ballot(lstv[i] < vv);
        int pos = __popc((unsigned)((lt >> (g * 16)) & 0xFFFFu));
        int nv = __builtin_amdgcn_update_dpp(0, __float_as_int(lstv[i]),
                                             0x101, 0xF, 0xF, true);
        int ni = __builtin_amdgcn_update_dpp(0, lsti[i],
                                             0x101, 0xF, 0xF, true);
        if (p <= pos - 2)      { lstv[i] = __int_as_float(nv); lsti[i] = ni; }
        else if (p == pos - 1) { lstv[i] = vv; lsti[i] = col; }
    };

    stage(0, 0);                                    // prologue: tile 0
    __syncthreads();                                // vmcnt drain + rowT ready

    for (int t = 0; t < 64; ++t) {
        const int m0 = t * 64;
        const int cur = t & 1;
        if (t < 63) stage(cur ^ 1, m0 + 64);        // prefetch next tile NOW

        float4 sqc = *(const float4*)&sq[b * NPTS + m0 + p * 4];

        float acc[2][4] = {{0.f,0.f,0.f,0.f},{0.f,0.f,0.f,0.f}};
#pragma unroll 8
        for (int c = 0; c < 64; ++c) {
            float2 rv = *(const float2*)&rowT[c][rbase];
            float4 cv = *(const float4*)&colT[cur][c * 64 + p * 4];
            float cc[4] = {cv.x, cv.y, cv.z, cv.w};
#pragma unroll
            for (int ci = 0; ci < 4; ++ci) {
                acc[0][ci] = fmaf(rv.x, cc[ci], acc[0][ci]);
                acc[1][ci] = fmaf(rv.y, cc[ci], acc[1][ci]);
            }
        }

        // transform: dist = 2*G - sq[col]
        float sqa[4] = {sqc.x, sqc.y, sqc.z, sqc.w};
#pragma unroll
        for (int i = 0; i < 2; ++i)
#pragma unroll
            for (int j = 0; j < 4; ++j)
                acc[i][j] = fmaf(2.f, acc[i][j], -sqa[j]);

        // ---- scan: 2 rows; lockstep pops across the 4 groups ----
#pragma unroll
        for (int i = 0; i < 2; ++i) {
            float v0 = acc[i][0], v1 = acc[i][1];
            float v2 = acc[i][2], v3 = acc[i][3];
            float vm = fmaxf(fmaxf(v0, v1), fmaxf(v2, v3));
            unsigned long long bal = __ballot(vm > thr[i]);
            unsigned mg = (unsigned)((bal >> (g * 16)) & 0xFFFFull);
            while (__any(mg != 0u)) {
                bool act = (mg != 0u);
                int srcp = act ? (__ffs(mg) - 1) : 0;
                mg &= (mg - 1u);                    // 0 stays 0
                int srcl = (g << 4) | srcp;
                float b0 = __shfl(v0, srcl);        // 4 parallel bcasts
                float b1 = __shfl(v1, srcl);
                float b2 = __shfl(v2, srcl);
                float b3 = __shfl(v3, srcl);
                if (act) {
                    int cb = m0 + srcp * 4;
                    if (b0 > thr[i]) ins(i, b0, cb + 0);
                    if (b1 > thr[i]) ins(i, b1, cb + 1);
                    if (b2 > thr[i]) ins(i, b2, cb + 2);
                    if (b3 > thr[i]) ins(i, b3, cb + 3);
                }
            }
            if (bal) thr[i] = __shfl(lstv[i], 0, 16);
        }
        // single barrier: own-wave vmcnt drain completes the prefetch of
        // colT[cur^1]; sync makes all waves' staging writes visible and
        // guarantees no wave re-stages colT[cur] before others leave it.
        __syncthreads();
    }

#pragma unroll
    for (int i = 0; i < 2; ++i) {                   // descending output
        int row = rbase + i;
        idxout[((size_t)(b * NPTS) + n0 + row) * KNN + (15 - p)] = lsti[i];
    }
}

// ----------------------------------------------- K3: P/Q precompute ---------
__global__ __launch_bounds__(256) void k_pq(const float* __restrict__ fea,
                                            const float* __restrict__ Wf1,
                                            const float* __restrict__ bf1,
                                            float* __restrict__ Pt,
                                            float* __restrict__ Qt) {
    __shared__ __align__(16) float feaT[64][64];    // [c][n]
    __shared__ __align__(16) float WT[64][132];     // [c][o'], o' in 0..127
    __shared__ float sb[64];

    const int b = blockIdx.y;
    const int n0 = blockIdx.x * 64;
    const int tid = threadIdx.x;
    const int to = tid & 15, tn = tid >> 4;
    const float* feab = fea + (size_t)b * NCH * NPTS;

#pragma unroll
    for (int i = 0; i < 4; ++i) {
        int e = i * 1024 + tid * 4;
        int c = e >> 6, nn = e & 63;
        *(float4*)&feaT[c][nn] = *(const float4*)&feab[c * NPTS + n0 + nn];
    }
#pragma unroll
    for (int i = 0; i < 8; ++i) {
        int g = tid * 32 + i * 4;
        int op = g >> 6, c = g & 63;
        const float* src = (op < 64) ? &Wf1[op * 128 + c]
                                     : &Wf1[(op - 64) * 128 + 64 + c];
        float4 w = *(const float4*)src;
        WT[c + 0][op] = w.x; WT[c + 1][op] = w.y;
        WT[c + 2][op] = w.z; WT[c + 3][op] = w.w;
    }
    if (tid < 64) sb[tid] = bf1[tid];
    __syncthreads();

    float acc[4][8];
#pragma unroll
    for (int ni = 0; ni < 4; ++ni)
#pragma unroll
        for (int oj = 0; oj < 8; ++oj) acc[ni][oj] = 0.f;

#pragma unroll 4
    for (int c = 0; c < 64; ++c) {
        float4 a  = *(const float4*)&feaT[c][tn * 4];
        float4 w0 = *(const float4*)&WT[c][to * 8];
        float4 w1 = *(const float4*)&WT[c][to * 8 + 4];
        float av[4] = {a.x, a.y, a.z, a.w};
        float wv[8] = {w0.x, w0.y, w0.z, w0.w, w1.x, w1.y, w1.z, w1.w};
#pragma unroll
        for (int ni = 0; ni < 4; ++ni)
#pragma unroll
            for (int oj = 0; oj < 8; ++oj)
                acc[ni][oj] = fmaf(av[ni], wv[oj], acc[ni][oj]);
    }

    const int opb = to * 8;
#pragma unroll
    for (int ni = 0; ni < 4; ++ni) {
        int n = n0 + tn * 4 + ni;
        size_t base = ((size_t)b * NPTS + n) * 64;
        if (opb < 64) {     // P half: add bias
            float4 o0, o1;
            o0.x = acc[ni][0] + sb[opb + 0]; o0.y = acc[ni][1] + sb[opb + 1];
            o0.z = acc[ni][2] + sb[opb + 2]; o0.w = acc[ni][3] + sb[opb + 3];
            o1.x = acc[ni][4] + sb[opb + 4]; o1.y = acc[ni][5] + sb[opb + 5];
            o1.z = acc[ni][6] + sb[opb + 6]; o1.w = acc[ni][7] + sb[opb + 7];
            *(float4*)&Pt[base + opb]     = o0;
            *(float4*)&Pt[base + opb + 4] = o1;
        } else {            // Q half: no bias
            float4 o0, o1;
            o0.x = acc[ni][0]; o0.y = acc[ni][1]; o0.z = acc[ni][2]; o0.w = acc[ni][3];
            o1.x = acc[ni][4]; o1.y = acc[ni][5]; o1.z = acc[ni][6]; o1.w = acc[ni][7];
            *(float4*)&Qt[base + opb - 64]     = o0;
            *(float4*)&Qt[base + opb - 64 + 4] = o1;
        }
    }
}

// -------------------------------------------- K4: fused MLP + max ----------
__global__ __launch_bounds__(256) void k_mlp(
    const float* __restrict__ xyz,
    const float* __restrict__ Pt, const float* __restrict__ Qt,
    const int* __restrict__ knnidx,
    const float* __restrict__ Wg1, const float* __restrict__ bg1,
    const float* __restrict__ Wg2, const float* __restrict__ bg2,
    const float* __restrict__ Wf2, const float* __restrict__ bf2,
    const float* __restrict__ Wf3, const float* __restrict__ bf3,
    float* __restrict__ out) {
    __shared__ __align__(16) float bufX[64][68];
    __shared__ __align__(16) float bufY[64][68];
    __shared__ __align__(16) float Wbuf[64][68];
    __shared__ __align__(16) float scratch[1280];  // geo[10][68] then pm[64][17]
    __shared__ float biasS[64];
    __shared__ int sidx[64];

    const int b = blockIdx.y;
    const int n0 = blockIdx.x * 4;
    const int tid = threadIdx.x;
    const int to = tid & 15, tp = tid >> 4;

    if (tid < 64)
        sidx[tid] = knnidx[((size_t)(b * NPTS + n0)) * KNN + tid];
    __syncthreads();

    // f1 = relu(P + Q_gather) into bufX [c][pair]
    {
        int pair = tid >> 2, q = tid & 3;
        int m = sidx[pair];
        int pt = pair >> 4;
        const float* pB = &Pt[((size_t)b * NPTS + n0 + pt) * 64];
        const float* qB = &Qt[((size_t)b * NPTS + m) * 64];
#pragma unroll
        for (int i = 0; i < 4; ++i) {
            int c0 = q * 16 + i * 4;
            float4 pv = *(const float4*)&pB[c0];
            float4 qv = *(const float4*)&qB[c0];
            bufX[c0 + 0][pair] = fmaxf(pv.x + qv.x, 0.f);
            bufX[c0 + 1][pair] = fmaxf(pv.y + qv.y, 0.f);
            bufX[c0 + 2][pair] = fmaxf(pv.z + qv.z, 0.f);
            bufX[c0 + 3][pair] = fmaxf(pv.w + qv.w, 0.f);
        }
    }
    // geo [10][68] into scratch
    if (tid < 64) {
        int pair = tid, pt = pair >> 4;
        int m = sidx[pair];
        const float* xb = xyz + (size_t)b * 3 * NPTS;
        float cx = xb[0 * NPTS + n0 + pt], cy = xb[1 * NPTS + n0 + pt], cz = xb[2 * NPTS + n0 + pt];
        float kx = xb[0 * NPTS + m], ky = xb[1 * NPTS + m], kz = xb[2 * NPTS + m];
        float rx = cx - kx, ry = cy - ky, rz = cz - kz;
        float d = sqrtf(rx * rx + ry * ry + rz * rz);
        scratch[0 * 68 + pair] = d;
        scratch[1 * 68 + pair] = cx; scratch[2 * 68 + pair] = cy; scratch[3 * 68 + pair] = cz;
        scratch[4 * 68 + pair] = kx; scratch[5 * 68 + pair] = ky; scratch[6 * 68 + pair] = kz;
        scratch[7 * 68 + pair] = rx; scratch[8 * 68 + pair] = ry; scratch[9 * 68 + pair] = rz;
    }

    auto stageW = [&](const float* W, const float* bv) {
#pragma unroll
        for (int i = 0; i < 4; ++i) {
            int g = tid * 16 + i * 4;
            int o = g >> 6, c = g & 63;
            float4 w = *(const float4*)&W[g];
            Wbuf[c + 0][o] = w.x; Wbuf[c + 1][o] = w.y;
            Wbuf[c + 2][o] = w.z; Wbuf[c + 3][o] = w.w;
        }
        if (tid < 64) biasS[tid] = bv[tid];
    };

    auto gemmPh = [&](const float* src, float* dst, int Kdim) {
        float acc[4][4] = {{0.f,0.f,0.f,0.f},{0.f,0.f,0.f,0.f},
                           {0.f,0.f,0.f,0.f},{0.f,0.f,0.f,0.f}};
#pragma unroll 2
        for (int c = 0; c < Kdim; ++c) {
            float4 w = *(const float4*)&Wbuf[c][to * 4];
            float4 a = *(const float4*)(src + c * 68 + tp * 4);
            float wr[4] = {w.x, w.y, w.z, w.w};
            float ar[4] = {a.x, a.y, a.z, a.w};
#pragma unroll
            for (int oi = 0; oi < 4; ++oi)
#pragma unroll
                for (int pj = 0; pj < 4; ++pj)
                    acc[oi][pj] = fmaf(wr[oi], ar[pj], acc[oi][pj]);
        }
#pragma unroll
        for (int oi = 0; oi < 4; ++oi) {
            float bo = biasS[to * 4 + oi];
            float4 o4;
            o4.x = fmaxf(acc[oi][0] + bo, 0.f);
            o4.y = fmaxf(acc[oi][1] + bo, 0.f);
            o4.z = fmaxf(acc[oi][2] + bo, 0.f);
            o4.w = fmaxf(acc[oi][3] + bo, 0.f);
            *(float4*)(dst + (to * 4 + oi) * 68 + tp * 4) = o4;
        }
    };

    stageW(Wf2, bf2);
    __syncthreads();
    gemmPh(&bufX[0][0], &bufY[0][0], 64);       // f2
    __syncthreads();
    stageW(Wf3, bf3);
    __syncthreads();
    gemmPh(&bufY[0][0], &bufX[0][0], 64);       // f3 -> bufX
    __syncthreads();
    {   // Wg1 is 64x10
        for (int e = tid; e < 640; e += 256) {
            int o = e / 10, c = e - o * 10;
            Wbuf[c][o] = Wg1[e];
        }
        if (tid < 64) biasS[tid] = bg1[tid];
    }
    __syncthreads();
    gemmPh(scratch, &bufY[0][0], 10);           // g1 -> bufY
    __syncthreads();
    stageW(Wg2, bg2);
    __syncthreads();
    {   // g2 GEMM with fused *f3 and partial max epilogue
        float acc[4][4] = {{0.f,0.f,0.f,0.f},{0.f,0.f,0.f,0.f},
                           {0.f,0.f,0.f,0.f},{0.f,0.f,0.f,0.f}};
#pragma unroll 2
        for (int c = 0; c < 64; ++c) {
            float4 w = *(const float4*)&Wbuf[c][to * 4];
            float4 a = *(const float4*)&bufY[c][tp * 4];
            float wr[4] = {w.x, w.y, w.z, w.w};
            float ar[4] = {a.x, a.y, a.z, a.w};
#pragma unroll
            for (int oi = 0; oi < 4; ++oi)
#pragma unroll
                for (int pj = 0; pj < 4; ++pj)
                    acc[oi][pj] = fmaf(wr[oi], ar[pj], acc[oi][pj]);
        }
#pragma unroll
        for (int oi = 0; oi < 4; ++oi) {
            int o = to * 4 + oi;
            float bo = biasS[o];
            float mx = -3.0e38f;
#pragma unroll
            for (int pj = 0; pj < 4; ++pj) {
                float g2v = fmaxf(acc[oi][pj] + bo, 0.f);
                float f3v = bufX[o][tp * 4 + pj];
                mx = fmaxf(mx, g2v * f3v);
            }
            scratch[o * 17 + tp] = mx;          // pm[64][17]
        }
    }
    __syncthreads();
    {
        int o = tid & 63, pt = tid >> 6;
        float m0_ = scratch[o * 17 + pt * 4 + 0];
        float m1  = scratch[o * 17 + pt * 4 + 1];
        float m2  = scratch[o * 17 + pt * 4 + 2];
        float m3  = scratch[o * 17 + pt * 4 + 3];
        out[((size_t)b * 64 + o) * NPTS + n0 + pt] =
            fmaxf(fmaxf(m0_, m1), fmaxf(m2, m3));
    }
}

// ---------------------------------------------------------------------------
extern "C" void kernel_launch(void* const* d_in, const int* in_sizes, int n_in,
                              void* d_out, int out_size, void* d_ws, size_t ws_size,
                              hipStream_t stream) {
    const float* xyz = (const float*)d_in[0];
    const float* fea = (const float*)d_in[1];
    const float* Wg1 = (const float*)d_in[2];
    const float* bg1 = (const float*)d_in[3];
    const float* Wg2 = (const float*)d_in[4];
    const float* bg2 = (const float*)d_in[5];
    const float* Wf1 = (const float*)d_in[6];
    const float* bf1 = (const float*)d_in[7];
    const float* Wf2 = (const float*)d_in[8];
    const float* bf2 = (const float*)d_in[9];
    const float* Wf3 = (const float*)d_in[10];
    const float* bf3 = (const float*)d_in[11];
    float* out = (float*)d_out;
    float* ws = (float*)d_ws;

    float* sq = ws + WS_SQ;
    float* Pt = ws + WS_PT;
    float* Qt = ws + WS_QT;
    int* idxw = (int*)(ws + WS_IDX);

    k_sq  <<<dim3(128),      dim3(256), 0, stream>>>(fea, sq);
    k_knn <<<dim3(128, 8),   dim3(256), 0, stream>>>(fea, sq, idxw);
    k_pq  <<<dim3(64, 8),    dim3(256), 0, stream>>>(fea, Wf1, bf1, Pt, Qt);
    k_mlp <<<dim3(1024, 8),  dim3(256), 0, stream>>>(xyz, Pt, Qt, idxw,
                                                     Wg1, bg1, Wg2, bg2,
                                                     Wf2, bf2, Wf3, bf3, out);
}